// Round 3
// baseline (888.522 us; speedup 1.0000x reference)
//
#include <hip/hip_runtime.h>
#include <hip/hip_bf16.h>

// SAGAN self-attention. B=4, C=64, H=W=128, N=16384, M=4096.
// Round 3: dtype self-detection (fp32 vs bf16 inputs) — round 1/2 NaN is
// consistent with fp32 buffers being read as bf16. All kernel bodies are
// templated on the element type; a 1-wave probe kernel writes a flag into ws.

#define NPIX 16384
#define MPIX 4096
#define CIN  64
#define CG   32
#define TM   128
#define TSTRIDE 44     // 44*4B = 176B, 16B-aligned

// ---------------- dtype probe ----------------
// Reads first 4096 u16 words of x as bf16. True bf16 N(0,1): max|v| < ~10,
// no NaN/Inf. fp32 data misread as bf16: low-half words have ~uniform top
// bits -> |v|>1e10 or exp=0xFF guaranteed within 4096 samples.
__global__ void detect_kernel(const void* __restrict__ x, int* __restrict__ flag) {
    const unsigned short* u = (const unsigned short*)x;
    int lane = threadIdx.x;          // 64 threads
    float mx = 0.f;
    for (int i = lane; i < 4096; i += 64) {
        unsigned short h = u[i];
        int e = (h >> 7) & 0xFF;
        if (e == 0xFF) mx = 3.0e38f;                       // NaN/Inf pattern
        unsigned int w = ((unsigned int)h) << 16;
        mx = fmaxf(mx, __uint_as_float(w & 0x7FFFFFFFu));
    }
    for (int off = 32; off > 0; off >>= 1)
        mx = fmaxf(mx, __shfl_down(mx, off));
    if (lane == 0) flag[0] = (mx > 1.0e10f) ? 1 : 0;       // 1 = fp32, 0 = bf16
}

// ---------------- Kernel A1: theta = w_theta @ x ----------------
template <typename T>
__device__ __forceinline__ void theta_body(
    const T* __restrict__ x, const T* __restrict__ w_theta,
    float* __restrict__ thetaW)
{
    __shared__ float W[CIN][8];
    int tid = threadIdx.x;
    for (int i = tid; i < CIN * 8; i += 256) {
        int j = i >> 6, c = i & 63;
        W[c][j] = (float)w_theta[j * CIN + c];
    }
    __syncthreads();

    int g = blockIdx.x * 256 + tid;
    int b = g >> 14;
    int n = g & (NPIX - 1);

    float acc[8];
#pragma unroll
    for (int j = 0; j < 8; j++) acc[j] = 0.f;

    const T* xp = x + (((size_t)b * CIN) << 14) + n;
    for (int c = 0; c < CIN; c++) {
        float xv = (float)xp[(size_t)c << 14];       // coalesced over n
        float4 w0 = *(const float4*)&W[c][0];        // broadcast
        float4 w1 = *(const float4*)&W[c][4];
        acc[0] += w0.x * xv; acc[1] += w0.y * xv;
        acc[2] += w0.z * xv; acc[3] += w0.w * xv;
        acc[4] += w1.x * xv; acc[5] += w1.y * xv;
        acc[6] += w1.z * xv; acc[7] += w1.w * xv;
    }
#pragma unroll
    for (int j = 0; j < 8; j++) thetaW[((b * 8 + j) << 14) + n] = acc[j];
}

__global__ __launch_bounds__(256) void theta_kernel(
    const void* __restrict__ x, const void* __restrict__ w_theta,
    float* __restrict__ thetaW, const int* __restrict__ flag)
{
    if (flag[0]) theta_body<float>((const float*)x, (const float*)w_theta, thetaW);
    else         theta_body<__hip_bfloat16>((const __hip_bfloat16*)x,
                                            (const __hip_bfloat16*)w_theta, thetaW);
}

// ------- Kernel A2: phiP/gP = maxpool2 of (w_phi @ x), (w_g @ x), fused -------
template <typename T>
__device__ __forceinline__ void phig_body(
    const T* __restrict__ x, const T* __restrict__ w_phi, const T* __restrict__ w_g,
    float* __restrict__ phiP, float* __restrict__ gP)
{
    __shared__ float W[CIN][40];   // j<8 phi, j<40 g
    int tid = threadIdx.x;
    for (int i = tid; i < CIN * 40; i += 256) {
        int c = i / 40, j = i % 40;
        W[c][j] = (j < 8) ? (float)w_phi[j * CIN + c]
                          : (float)w_g[(j - 8) * CIN + c];
    }
    __syncthreads();

    int gI = blockIdx.x * 256 + tid;          // b*M + m
    int b  = gI >> 12;
    int m  = gI & (MPIX - 1);
    int mh = m >> 6, mw = m & 63;

    float pooled[40];
#pragma unroll
    for (int j = 0; j < 40; j++) pooled[j] = -3.0e38f;

    const T* xb = x + (((size_t)b * CIN) << 14);
#pragma unroll
    for (int py = 0; py < 2; py++) {
#pragma unroll
        for (int px = 0; px < 2; px++) {
            int pix = (2 * mh + py) * 128 + 2 * mw + px;
            float acc[40];
#pragma unroll
            for (int j = 0; j < 40; j++) acc[j] = 0.f;
            for (int c = 0; c < CIN; c++) {
                float xv = (float)xb[(c << 14) + pix];
                const float4* wr = (const float4*)&W[c][0];
#pragma unroll
                for (int jq = 0; jq < 10; jq++) {
                    float4 w4 = wr[jq];
                    acc[4 * jq + 0] += w4.x * xv;
                    acc[4 * jq + 1] += w4.y * xv;
                    acc[4 * jq + 2] += w4.z * xv;
                    acc[4 * jq + 3] += w4.w * xv;
                }
            }
#pragma unroll
            for (int j = 0; j < 40; j++) pooled[j] = fmaxf(pooled[j], acc[j]);
        }
    }
#pragma unroll
    for (int j = 0; j < 8; j++)  phiP[((b * 8 + j) << 12) + m] = pooled[j];
#pragma unroll
    for (int j = 0; j < 32; j++) gP[((b * 32 + j) << 12) + m]  = pooled[8 + j];
}

__global__ __launch_bounds__(256) void phig_pool_kernel(
    const void* __restrict__ x, const void* __restrict__ w_phi,
    const void* __restrict__ w_g,
    float* __restrict__ phiP, float* __restrict__ gP, const int* __restrict__ flag)
{
    if (flag[0]) phig_body<float>((const float*)x, (const float*)w_phi,
                                  (const float*)w_g, phiP, gP);
    else         phig_body<__hip_bfloat16>((const __hip_bfloat16*)x,
                                           (const __hip_bfloat16*)w_phi,
                                           (const __hip_bfloat16*)w_g, phiP, gP);
}

// ---------------- Kernel C: attention + w_o projection + residual ----------------
template <typename T>
__device__ __forceinline__ void attn_body(
    const float* __restrict__ thetaW, const float* __restrict__ phiP,
    const float* __restrict__ gP, const T* __restrict__ w_o,
    const T* __restrict__ gamma, const T* __restrict__ x, T* __restrict__ out)
{
    __shared__ float tile[TM * TSTRIDE];   // [mm][0..7]=phi, [8..39]=g
    __shared__ float Op[CG * 4 * 64];      // [c][q][r]
    __shared__ float Lp[4 * 64];           // [q][r]
    __shared__ float wo[64 * 32];          // [cc][c]

    int tid = threadIdx.x;
    int r = tid & 63, q = tid >> 6;
    int wg = blockIdx.x;
    int b  = wg >> 8;
    int n0 = (wg & 255) << 6;
    int n  = n0 + r;

    for (int i = tid; i < 64 * 32; i += 256) wo[i] = (float)w_o[i];

    float th[8];
#pragma unroll
    for (int c = 0; c < 8; c++) th[c] = thetaW[((b * 8 + c) << 14) + n];

    float l = 0.f;
    float o[CG];
#pragma unroll
    for (int c = 0; c < CG; c++) o[c] = 0.f;

    for (int mt = 0; mt < MPIX / TM; mt++) {
        int m0 = mt * TM;
        __syncthreads();   // prev tile reads done (covers wo load at iter 0)
        for (int i = tid; i < 40 * TM; i += 256) {
            int c40 = i >> 7;
            int mm  = i & (TM - 1);
            float v = (c40 < 8) ? phiP[((b * 8 + c40) << 12) + m0 + mm]
                                : gP[((b * 32 + (c40 - 8)) << 12) + m0 + mm];
            tile[mm * TSTRIDE + c40] = v;
        }
        __syncthreads();
        for (int k = 0; k < TM / 4; k++) {
            int mm = (k << 2) | q;
            const float4* tp = (const float4*)&tile[mm * TSTRIDE];  // broadcast
            float4 p0 = tp[0], p1 = tp[1];
            float s = th[0] * p0.x + th[1] * p0.y + th[2] * p0.z + th[3] * p0.w
                    + th[4] * p1.x + th[5] * p1.y + th[6] * p1.z + th[7] * p1.w;
            float p = __expf(s - 10.0f);   // constant shift cancels in softmax
            l += p;
#pragma unroll
            for (int cg = 0; cg < 8; cg++) {
                float4 gv = tp[2 + cg];
                o[4 * cg + 0] += p * gv.x;
                o[4 * cg + 1] += p * gv.y;
                o[4 * cg + 2] += p * gv.z;
                o[4 * cg + 3] += p * gv.w;
            }
        }
    }

    // cross-partition reduce
#pragma unroll
    for (int c = 0; c < CG; c++) Op[(c * 4 + q) * 64 + r] = o[c];
    Lp[q * 64 + r] = l;
    __syncthreads();

    float ltot = Lp[0 * 64 + r] + Lp[1 * 64 + r] + Lp[2 * 64 + r] + Lp[3 * 64 + r];
    float linv = 1.0f / ltot;
    float attn_r[8];
#pragma unroll
    for (int j = 0; j < 8; j++) {
        int c = 8 * q + j;
        attn_r[j] = (Op[(c * 4 + 0) * 64 + r] + Op[(c * 4 + 1) * 64 + r]
                   + Op[(c * 4 + 2) * 64 + r] + Op[(c * 4 + 3) * 64 + r]) * linv;
    }
    __syncthreads();
    float* attn = tile;                 // overlay, [r][33]
#pragma unroll
    for (int j = 0; j < 8; j++) attn[r * 33 + 8 * q + j] = attn_r[j];
    __syncthreads();

    float gam = (float)gamma[0];
    float a[32];
#pragma unroll
    for (int c = 0; c < 32; c++) a[c] = attn[r * 33 + c];

    for (int ci = 0; ci < 16; ci++) {
        int cc = q * 16 + ci;
        const float4* wr = (const float4*)&wo[cc * 32];
        float acc = 0.f;
#pragma unroll
        for (int cq = 0; cq < 8; cq++) {
            float4 w4 = wr[cq];
            acc += w4.x * a[4 * cq + 0] + w4.y * a[4 * cq + 1]
                 + w4.z * a[4 * cq + 2] + w4.w * a[4 * cq + 3];
        }
        size_t gi = (((size_t)(b * 64 + cc)) << 14) + n;    // coalesced over r
        out[gi] = (T)(gam * acc + (float)x[gi]);
    }
}

__global__ __launch_bounds__(256) void attn_kernel(
    const float* __restrict__ thetaW, const float* __restrict__ phiP,
    const float* __restrict__ gP, const void* __restrict__ w_o,
    const void* __restrict__ gamma, const void* __restrict__ x,
    void* __restrict__ out, const int* __restrict__ flag)
{
    if (flag[0]) attn_body<float>(thetaW, phiP, gP, (const float*)w_o,
                                  (const float*)gamma, (const float*)x, (float*)out);
    else         attn_body<__hip_bfloat16>(thetaW, phiP, gP,
                                           (const __hip_bfloat16*)w_o,
                                           (const __hip_bfloat16*)gamma,
                                           (const __hip_bfloat16*)x,
                                           (__hip_bfloat16*)out);
}

extern "C" void kernel_launch(void* const* d_in, const int* in_sizes, int n_in,
                              void* d_out, int out_size, void* d_ws, size_t ws_size,
                              hipStream_t stream) {
    const void* x       = d_in[0];
    const void* w_theta = d_in[1];
    const void* w_phi   = d_in[2];
    const void* w_g     = d_in[3];
    const void* w_o     = d_in[4];
    const void* gamma   = d_in[5];

    float* ws     = (float*)d_ws;
    int*   flag   = (int*)ws;                // ws[0]
    float* thetaW = ws + 16;                 // 4*8*16384 = 524288 floats (2 MB)
    float* phiP   = thetaW + 524288;         // 4*8*4096  = 131072 floats (0.5 MB)
    float* gP     = phiP + 131072;           // 4*32*4096 = 524288 floats (2 MB)
    // total ~4.5 MB + 64 B

    detect_kernel<<<1, 64, 0, stream>>>(x, flag);
    theta_kernel<<<256, 256, 0, stream>>>(x, w_theta, thetaW, flag);
    phig_pool_kernel<<<64, 256, 0, stream>>>(x, w_phi, w_g, phiP, gP, flag);
    attn_kernel<<<1024, 256, 0, stream>>>(thetaW, phiP, gP, w_o, gamma, x,
                                          d_out, flag);
}

// Round 4
// 293.564 us; speedup vs baseline: 3.0267x; 3.0267x over previous
//
#include <hip/hip_runtime.h>
#include <hip/hip_bf16.h>

// SAGAN self-attention, MI355X. B=4, C=64, H=W=128, N=16384, M=4096.
// Inputs/outputs are fp32 (round-3 evidence: fp32 path passed, absmax 0.0156).
// Round 4: MFMA-based PV (17.2 GFLOP) + VALU fp32 scores computed directly in
// MFMA B-fragment layout (no P transpose). Fused proj (theta/phi/g + pool).

#define NPIX 16384
#define MPIX 4096

typedef __attribute__((ext_vector_type(4))) float f32x4;
typedef __attribute__((ext_vector_type(8))) short s16x8;   // 8 bf16 in 4 VGPRs

__device__ __forceinline__ unsigned short f32_bf16(float f) {
    unsigned int u = __float_as_uint(f);
    return (unsigned short)((u + 0x7fffu + ((u >> 16) & 1u)) >> 16);  // RNE
}
__device__ __forceinline__ float blo(unsigned int d) { return __uint_as_float(d << 16); }
__device__ __forceinline__ float bhi(unsigned int d) { return __uint_as_float(d & 0xffff0000u); }

// ---------- Kernel A: fused theta/phi/g 1x1 conv + 2x2 maxpool on phi/g ----------
// Grid: 256 blocks = b*64 + mh. Block: 256 thr = 64 m_local x 4 pixels.
__global__ __launch_bounds__(256) void proj_kernel(
    const float* __restrict__ x,
    const float* __restrict__ w_theta, const float* __restrict__ w_phi,
    const float* __restrict__ w_g,
    float* __restrict__ thetaW,            // [b][n][8] f32
    __hip_bfloat16* __restrict__ phiB,     // [b][m][8] bf16
    __hip_bfloat16* __restrict__ gB)       // [b][32][4096] bf16
{
    __shared__ float W[64][48];   // [c][j]: j<8 theta, <16 phi, <48 g
    int tid = threadIdx.x;
    for (int i = tid; i < 64 * 48; i += 256) {
        int c = i / 48, j = i % 48;
        float v;
        if (j < 8)       v = w_theta[j * 64 + c];
        else if (j < 16) v = w_phi[(j - 8) * 64 + c];
        else             v = w_g[(j - 16) * 64 + c];
        W[c][j] = v;
    }
    __syncthreads();

    int bx = blockIdx.x;
    int b = bx >> 6, mh = bx & 63;
    int ml = tid >> 2;                 // m within row, 0..63
    int pix = tid & 3;
    int py = pix >> 1, px = pix & 1;
    int n = (2 * mh + py) * 128 + 2 * ml + px;

    float accT[8], accP[40];
#pragma unroll
    for (int j = 0; j < 8; j++) accT[j] = 0.f;
#pragma unroll
    for (int j = 0; j < 40; j++) accP[j] = 0.f;

    const float* xb = x + ((size_t)b << 20);
    for (int c = 0; c < 64; c++) {
        float xv = xb[(c << 14) + n];
        const float4* wr = (const float4*)&W[c][0];
        float4 w0 = wr[0], w1 = wr[1];
        accT[0] += w0.x * xv; accT[1] += w0.y * xv; accT[2] += w0.z * xv; accT[3] += w0.w * xv;
        accT[4] += w1.x * xv; accT[5] += w1.y * xv; accT[6] += w1.z * xv; accT[7] += w1.w * xv;
#pragma unroll
        for (int jq = 0; jq < 10; jq++) {
            float4 w4 = wr[2 + jq];
            accP[4 * jq + 0] += w4.x * xv;
            accP[4 * jq + 1] += w4.y * xv;
            accP[4 * jq + 2] += w4.z * xv;
            accP[4 * jq + 3] += w4.w * xv;
        }
    }
    // theta: [n][8] f32, 32B per thread
    float4* tp = (float4*)(thetaW + (((size_t)b << 14) + n) * 8);
    tp[0] = make_float4(accT[0], accT[1], accT[2], accT[3]);
    tp[1] = make_float4(accT[4], accT[5], accT[6], accT[7]);
    // maxpool over the 4 pixels (lanes tid^1, tid^2)
#pragma unroll
    for (int j = 0; j < 40; j++) {
        float v = accP[j];
        v = fmaxf(v, __shfl_xor(v, 1));
        v = fmaxf(v, __shfl_xor(v, 2));
        accP[j] = v;
    }
    if (pix == 0) {
        int m = mh * 64 + ml;
        unsigned int pk[4];
#pragma unroll
        for (int t = 0; t < 4; t++)
            pk[t] = (unsigned int)f32_bf16(accP[2 * t]) |
                    ((unsigned int)f32_bf16(accP[2 * t + 1]) << 16);
        *(uint4*)(phiB + ((size_t)(b * 4096 + m)) * 8) = make_uint4(pk[0], pk[1], pk[2], pk[3]);
#pragma unroll
        for (int j = 0; j < 32; j++) {
            unsigned short u = f32_bf16(accP[8 + j]);
            ((unsigned short*)gB)[((size_t)(b * 32 + j) << 12) + m] = u;
        }
    }
}

// ---------- Kernel B: flash attention + w_o projection + residual ----------
// Grid: 512 blocks = b*128 + n-tile(128). Block: 256 thr = 4 waves x 32 n.
// Wave: lane = q*16 + nl; lane owns n = nw + ng*16 + nl (ng=0,1), m-octet q.
// PV per 32-m chunk: D[c][n] += sum_m g[c][m] * P[n][m] via mfma_16x16x32_bf16,
//   A = g (A[row=lane&15=c][k=q*8+j=m]), B = P (B[k=q*8+j=m][col=lane&15=n]).
__global__ __launch_bounds__(256) void attn_kernel(
    const float* __restrict__ thetaW, const __hip_bfloat16* __restrict__ phiB,
    const __hip_bfloat16* __restrict__ gB,
    const float* __restrict__ w_o, const float* __restrict__ gamma,
    const float* __restrict__ x, float* __restrict__ out)
{
    __shared__ __align__(16) unsigned char smem[10752];
    __hip_bfloat16* phi_s = (__hip_bfloat16*)smem;            // [128][8]   2048 B
    unsigned char*  g_s   = smem + 2048;                      // [32][136]  8704 B (stride 272 B)
    unsigned char*  O_s   = smem;                             // epilogue overlay [128][40] bf16 (stride 80 B)

    int tid  = threadIdx.x;
    int lane = tid & 63, w = tid >> 6;
    int q = lane >> 4, nl = lane & 15;
    int bx = blockIdx.x;
    int b  = bx >> 7;
    int n0 = (bx & 127) << 7;
    int nw = n0 + w * 32;

    // theta for this lane's two n rows (fp32, registers, once)
    float th[2][8];
#pragma unroll
    for (int ng = 0; ng < 2; ng++) {
        const float4* tp = (const float4*)(thetaW + (((size_t)b << 14) + nw + ng * 16 + nl) * 8);
        float4 t0 = tp[0], t1 = tp[1];
        th[ng][0] = t0.x; th[ng][1] = t0.y; th[ng][2] = t0.z; th[ng][3] = t0.w;
        th[ng][4] = t1.x; th[ng][5] = t1.y; th[ng][6] = t1.z; th[ng][7] = t1.w;
    }

    f32x4 acc[2][2];   // [ng][c-grp]
#pragma unroll
    for (int a = 0; a < 2; a++)
#pragma unroll
        for (int g2 = 0; g2 < 2; g2++) acc[a][g2] = (f32x4){0.f, 0.f, 0.f, 0.f};
    float l[2] = {0.f, 0.f};

    const __hip_bfloat16* phig = phiB + ((size_t)b << 15);    // b*4096*8
    const __hip_bfloat16* ggb  = gB + ((size_t)b << 17);      // b*32*4096

    for (int st = 0; st < 32; st++) {
        int m0 = st << 7;
        __syncthreads();
        {   // stage phi: 128 m x 8 c bf16 = 2 KB
            const uint2* src = (const uint2*)(phig + (size_t)m0 * 8);
            ((uint2*)phi_s)[tid] = src[tid];
        }
        {   // stage g: 32 c x 128 m bf16, LDS stride 272 B
            int c = tid >> 3, k = (tid & 7) << 4;
            const uint4* src = (const uint4*)(ggb + ((size_t)c << 12) + m0 + k);
            uint4* dst = (uint4*)(g_s + c * 272 + k * 2);
            dst[0] = src[0];
            dst[1] = src[1];
        }
        __syncthreads();
#pragma unroll
        for (int cc = 0; cc < 4; cc++) {
            int mb = (cc << 5) + (q << 3);     // lane's m-octet base in stage
            unsigned short pb0[8], pb1[8];
#pragma unroll
            for (int j = 0; j < 8; j++) {
                uint4 rw = *(const uint4*)(phi_s + (size_t)(mb + j) * 8);
                float f0 = blo(rw.x), f1 = bhi(rw.x), f2 = blo(rw.y), f3 = bhi(rw.y);
                float f4 = blo(rw.z), f5 = bhi(rw.z), f6 = blo(rw.w), f7 = bhi(rw.w);
                float s0 = f0 * th[0][0] + f1 * th[0][1] + f2 * th[0][2] + f3 * th[0][3]
                         + f4 * th[0][4] + f5 * th[0][5] + f6 * th[0][6] + f7 * th[0][7];
                float s1 = f0 * th[1][0] + f1 * th[1][1] + f2 * th[1][2] + f3 * th[1][3]
                         + f4 * th[1][4] + f5 * th[1][5] + f6 * th[1][6] + f7 * th[1][7];
                float p0 = __expf(s0 - 10.f);     // constant shift cancels in softmax
                float p1 = __expf(s1 - 10.f);
                l[0] += p0; l[1] += p1;
                pb0[j] = f32_bf16(p0); pb1[j] = f32_bf16(p1);
            }
            s16x8 P0, P1, G0, G1;
#pragma unroll
            for (int j = 0; j < 8; j++) { P0[j] = (short)pb0[j]; P1[j] = (short)pb1[j]; }
            G0 = *(const s16x8*)(g_s + nl * 272 + mb * 2);
            G1 = *(const s16x8*)(g_s + (nl + 16) * 272 + mb * 2);
            acc[0][0] = __builtin_amdgcn_mfma_f32_16x16x32_bf16(G0, P0, acc[0][0], 0, 0, 0);
            acc[0][1] = __builtin_amdgcn_mfma_f32_16x16x32_bf16(G1, P0, acc[0][1], 0, 0, 0);
            acc[1][0] = __builtin_amdgcn_mfma_f32_16x16x32_bf16(G0, P1, acc[1][0], 0, 0, 0);
            acc[1][1] = __builtin_amdgcn_mfma_f32_16x16x32_bf16(G1, P1, acc[1][1], 0, 0, 0);
        }
    }

    // softmax denominators: reduce over the 4 m-octet quads (lane bits 4,5)
#pragma unroll
    for (int ng = 0; ng < 2; ng++) {
        float v = l[ng];
        v += __shfl_xor(v, 16);
        v += __shfl_xor(v, 32);
        float linv = 1.0f / v;
        acc[ng][0] *= linv;
        acc[ng][1] *= linv;
    }

    __syncthreads();   // all g_s/phi_s reads done; overlay O_s
    // write O^T[c][n] -> O_s[n_loc][c] bf16, stride 80 B; lane's 4 c are consecutive
#pragma unroll
    for (int ng = 0; ng < 2; ng++) {
        int n_loc = w * 32 + ng * 16 + nl;
#pragma unroll
        for (int g2 = 0; g2 < 2; g2++) {
            unsigned int lo32 = (unsigned int)f32_bf16(acc[ng][g2][0]) |
                                ((unsigned int)f32_bf16(acc[ng][g2][1]) << 16);
            unsigned int hi32 = (unsigned int)f32_bf16(acc[ng][g2][2]) |
                                ((unsigned int)f32_bf16(acc[ng][g2][3]) << 16);
            *(uint2*)(O_s + n_loc * 80 + (g2 * 16 + q * 4) * 2) = make_uint2(lo32, hi32);
        }
    }
    // w_o A-fragments from global (fp32 -> bf16): A[row=cc=16*grp+nl][k=c=q*8+j]
    s16x8 WO[4];
#pragma unroll
    for (int g4 = 0; g4 < 4; g4++) {
        const float4* wr = (const float4*)(w_o + (size_t)(g4 * 16 + nl) * 32 + q * 8);
        float4 a0 = wr[0], a1 = wr[1];
        WO[g4][0] = (short)f32_bf16(a0.x); WO[g4][1] = (short)f32_bf16(a0.y);
        WO[g4][2] = (short)f32_bf16(a0.z); WO[g4][3] = (short)f32_bf16(a0.w);
        WO[g4][4] = (short)f32_bf16(a1.x); WO[g4][5] = (short)f32_bf16(a1.y);
        WO[g4][6] = (short)f32_bf16(a1.z); WO[g4][7] = (short)f32_bf16(a1.w);
    }
    float gam = gamma[0];
    __syncthreads();

#pragma unroll
    for (int ng = 0; ng < 2; ng++) {
        int n_loc_base = w * 32 + ng * 16;
        // B-frag: B[k=c=q*8+j][col=n=nl] = O[c][n] from O_s[n_loc_base+nl][q*8..+7]
        s16x8 OB = *(const s16x8*)(O_s + (n_loc_base + nl) * 80 + q * 16);
#pragma unroll
        for (int g4 = 0; g4 < 4; g4++) {
            f32x4 d = (f32x4){0.f, 0.f, 0.f, 0.f};
            d = __builtin_amdgcn_mfma_f32_16x16x32_bf16(WO[g4], OB, d, 0, 0, 0);
            // D[row=cc=q*4+r+16*g4][col=n=nl]
#pragma unroll
            for (int r = 0; r < 4; r++) {
                int cc = g4 * 16 + q * 4 + r;
                size_t gi = (((size_t)(b * 64 + cc)) << 14) + n0 + n_loc_base + nl;
                out[gi] = gam * d[r] + x[gi];
            }
        }
    }
}

extern "C" void kernel_launch(void* const* d_in, const int* in_sizes, int n_in,
                              void* d_out, int out_size, void* d_ws, size_t ws_size,
                              hipStream_t stream) {
    const float* x       = (const float*)d_in[0];
    const float* w_theta = (const float*)d_in[1];
    const float* w_phi   = (const float*)d_in[2];
    const float* w_g     = (const float*)d_in[3];
    const float* w_o     = (const float*)d_in[4];
    const float* gamma   = (const float*)d_in[5];
    float* out = (float*)d_out;

    float* ws = (float*)d_ws;
    float*          thetaW = ws;                                   // 4*16384*8 f32 = 2 MB
    __hip_bfloat16* phiB   = (__hip_bfloat16*)(ws + 524288);       // 4*4096*8 bf16 = 256 KB
    __hip_bfloat16* gB     = phiB + 131072;                        // 4*32*4096 bf16 = 1 MB
    // total ~3.25 MB

    proj_kernel<<<256, 256, 0, stream>>>(x, w_theta, w_phi, w_g, thetaW, phiB, gB);
    attn_kernel<<<512, 256, 0, stream>>>(thetaW, phiB, gB, w_o, gamma, x, out);
}

// Round 6
// 183.551 us; speedup vs baseline: 4.8407x; 1.5994x over previous
//
#include <hip/hip_runtime.h>
#include <hip/hip_bf16.h>

// SAGAN self-attention, MI355X gfx950. B=4, C=64, H=W=128, N=16384, M=4096.
// fp32 in/out. Round 6: all-MFMA pipeline (round-5 design; fixed __exp2f ->
// __builtin_amdgcn_exp2f, the v_exp_f32 intrinsic).
//  proj: 48x64x65536 bf16 GEMM (theta pre-scaled by log2e), fused 2x2 maxpool.
//  attn: score MFMA (K slot c=8 carries softmax shift: theta row=-14.44, phi col=1.0)
//        -> exp2 -> P via per-wave LDS strip -> PV MFMA -> w_o MFMA epilogue.
// Verified layouts (round 4): A[row=lane&15][k=quad*8+j], B[k=quad*8+j][col=lane&15],
// C/D[row=quad*4+reg][col=lane&15].

#define NPIX 16384
#define MPIX 4096

typedef __attribute__((ext_vector_type(4))) float f32x4;
typedef __attribute__((ext_vector_type(8))) short s16x8;

__device__ __forceinline__ unsigned short f32_bf16(float f) {
    unsigned int u = __float_as_uint(f);
    return (unsigned short)((u + 0x7fffu + ((u >> 16) & 1u)) >> 16);  // RNE
}
__device__ __forceinline__ unsigned int pk_bf16(float a, float b) {
    return (unsigned int)f32_bf16(a) | ((unsigned int)f32_bf16(b) << 16);
}

// ---------------- proj: theta/phi/g projections + pool, via MFMA ----------------
// Grid 256 = b(4) x mh(64) [pooled row -> source rows 2mh,2mh+1]. 256 thr.
// Channel tiles: CT0 = theta(0..7)+phi(8..15), CT1/CT2 = g(0..15 / 16..31).
__global__ __launch_bounds__(256) void proj_kernel(
    const float* __restrict__ x,
    const float* __restrict__ w_theta, const float* __restrict__ w_phi,
    const float* __restrict__ w_g,
    __hip_bfloat16* __restrict__ thG,   // [b][8][16384]  (theta * log2e)
    __hip_bfloat16* __restrict__ phG,   // [b][4096][32]  (c8=1.0, c9..31=0)
    __hip_bfloat16* __restrict__ gG)    // [b][32][4096]
{
    __shared__ __align__(16) unsigned short x_s[256 * 72];  // [pix][c], stride 144 B
    int tid = threadIdx.x;
    int bx = blockIdx.x;
    int b = bx >> 6, mh = bx & 63;

    // phase 1: load x columns, cvt bf16, transpose into x_s[pix][c]
    {
        int pix = tid;
        int py = pix >> 7, px = pix & 127;
        const float* xp = x + ((size_t)b << 20) + (size_t)(2 * mh + py) * 128 + px;
        unsigned short* row = x_s + pix * 72;
        for (int c0 = 0; c0 < 64; c0 += 16) {
            float v[16];
#pragma unroll
            for (int c = 0; c < 16; c++) v[c] = xp[(size_t)(c0 + c) << 14];
            unsigned int pk[8];
#pragma unroll
            for (int h = 0; h < 8; h++) pk[h] = pk_bf16(v[2 * h], v[2 * h + 1]);
            *(uint4*)(row + c0)     = make_uint4(pk[0], pk[1], pk[2], pk[3]);
            *(uint4*)(row + c0 + 8) = make_uint4(pk[4], pk[5], pk[6], pk[7]);
        }
    }

    int lane = tid & 63, w = tid >> 6;
    int q = lane >> 4, nl = lane & 15;

    // weight A-frags: A[row=ch_local=nl][k = 32*ks + 8q + j]
    s16x8 A[3][2];
#pragma unroll
    for (int CT = 0; CT < 3; CT++) {
        const float* wsrc;
        float scale = 1.0f;
        if (CT == 0) {
            if (nl < 8) { wsrc = w_theta + nl * 64; scale = 1.44269504f; }
            else        { wsrc = w_phi + (nl - 8) * 64; }
        } else if (CT == 1) wsrc = w_g + nl * 64;
        else                wsrc = w_g + (16 + nl) * 64;
#pragma unroll
        for (int ks = 0; ks < 2; ks++) {
            const float4* p4 = (const float4*)(wsrc + 32 * ks + 8 * q);
            float4 a0 = p4[0], a1 = p4[1];
            s16x8 f;
            f[0] = (short)f32_bf16(a0.x * scale); f[1] = (short)f32_bf16(a0.y * scale);
            f[2] = (short)f32_bf16(a0.z * scale); f[3] = (short)f32_bf16(a0.w * scale);
            f[4] = (short)f32_bf16(a1.x * scale); f[5] = (short)f32_bf16(a1.y * scale);
            f[6] = (short)f32_bf16(a1.z * scale); f[7] = (short)f32_bf16(a1.w * scale);
            A[CT][ks] = f;
        }
    }
    __syncthreads();

    // phase 2: MFMA. wave w owns pix-tiles {2w, 2w+1, 2w+8, 2w+9}
    int Tl[4] = {2 * w, 2 * w + 1, 2 * w + 8, 2 * w + 9};
    f32x4 acc[3][4];
#pragma unroll
    for (int ti = 0; ti < 4; ti++) {
        const unsigned short* rb = x_s + (16 * Tl[ti] + nl) * 72;
        s16x8 B0 = *(const s16x8*)(rb + 8 * q);
        s16x8 B1 = *(const s16x8*)(rb + 32 + 8 * q);
#pragma unroll
        for (int CT = 0; CT < 3; CT++) {
            f32x4 d = (f32x4){0.f, 0.f, 0.f, 0.f};
            d = __builtin_amdgcn_mfma_f32_16x16x32_bf16(A[CT][0], B0, d, 0, 0, 0);
            d = __builtin_amdgcn_mfma_f32_16x16x32_bf16(A[CT][1], B1, d, 0, 0, 0);
            acc[CT][ti] = d;
        }
    }

    // theta store: CT0, q<2 -> ch=4q+r, [c][n] layout (pre-scaled by log2e)
    if (q < 2) {
        unsigned short* thb = (unsigned short*)thG + ((size_t)b * 8 << 14);
#pragma unroll
        for (int ti = 0; ti < 4; ti++) {
            int T = Tl[ti];
            int n = (2 * mh + (T >> 3)) * 128 + ((T & 7) * 16 + nl);
#pragma unroll
            for (int r = 0; r < 4; r++)
                thb[((4 * q + r) << 14) + n] = f32_bf16(acc[0][ti][r]);
        }
    }

    // 2x2 maxpool: py-pair = (ti, ti+2), px-pair = shfl_xor(1)
    f32x4 pool[3][2];
#pragma unroll
    for (int CT = 0; CT < 3; CT++)
#pragma unroll
        for (int i = 0; i < 2; i++) {
#pragma unroll
            for (int r = 0; r < 4; r++) {
                float a = fmaxf(acc[CT][i][r], acc[CT][i + 2][r]);
                pool[CT][i][r] = fmaxf(a, __shfl_xor(a, 1));
            }
        }

    bool evn = (nl & 1) == 0;
#pragma unroll
    for (int i = 0; i < 2; i++) {
        int m = mh * 64 + 16 * w + 8 * i + (nl >> 1);
        unsigned short* pr = (unsigned short*)phG + ((size_t)(b * 4096 + m)) * 32;
        if (evn) {
            if (q >= 2) {   // phi channels 4(q-2)+r
                uint2 pv;
                pv.x = pk_bf16(pool[0][i][0], pool[0][i][1]);
                pv.y = pk_bf16(pool[0][i][2], pool[0][i][3]);
                *(uint2*)(pr + (q - 2) * 4) = pv;
            }
#pragma unroll
            for (int CT = 1; CT < 3; CT++) {
#pragma unroll
                for (int r = 0; r < 4; r++) {
                    int cg = 16 * (CT - 1) + 4 * q + r;
                    ((unsigned short*)gG)[((size_t)(b * 32 + cg) << 12) + m] =
                        f32_bf16(pool[CT][i][r]);
                }
            }
        } else {
            if (q == 2)      *(uint4*)(pr + 8)  = make_uint4(0x3f80u, 0, 0, 0); // c8=1.0
            else if (q == 3) *(uint4*)(pr + 16) = make_uint4(0, 0, 0, 0);
            else if (q == 1) *(uint4*)(pr + 24) = make_uint4(0, 0, 0, 0);
        }
    }
}

// ---------------- attn: score MFMA -> exp2 -> PV MFMA -> w_o MFMA ----------------
// Grid 512 = b(4) x n-tile(128). 256 thr = 4 waves x 32 n.
__global__ __launch_bounds__(256) void attn_kernel(
    const __hip_bfloat16* __restrict__ thG, const __hip_bfloat16* __restrict__ phG,
    const __hip_bfloat16* __restrict__ gG,
    const float* __restrict__ w_o, const float* __restrict__ gamma,
    const float* __restrict__ x, float* __restrict__ out)
{
    __shared__ __align__(16) unsigned char smem[16896 + 10240];
    unsigned char* g_s = smem;                  // [32][528B]  (256 m bf16 + pad)
    unsigned char* P_s = smem + 16896;          // per-wave [32n][80B] (32 m bf16 + pad)
    unsigned char* O_s = smem;                  // epilogue overlay [128][80B]

    int tid = threadIdx.x, lane = tid & 63, w = tid >> 6;
    int q = lane >> 4, nl = lane & 15;
    int bx = blockIdx.x;
    int b  = bx >> 7;
    int n0 = (bx & 127) << 7;
    int nw = n0 + w * 32;

    // theta B-frags (once): B[k=c=8q+j][col=n]; c=8 carries shift -14.44, c>8 = 0
    const unsigned short* thb = (const unsigned short*)thG + ((size_t)b * 8 << 14);
    s16x8 BT[2];
#pragma unroll
    for (int ng = 0; ng < 2; ng++) {
        int n = nw + 16 * ng + nl;
        s16x8 f;
#pragma unroll
        for (int j = 0; j < 8; j++) {
            int c = 8 * q + j;
            unsigned short v;
            if (c < 8)       v = thb[(c << 14) + n];
            else if (c == 8) v = 0xC167u;          // bf16(-14.4375): shift, cancels
            else             v = 0;
            f[j] = (short)v;
        }
        BT[ng] = f;
    }

    f32x4 acc[2][2];
#pragma unroll
    for (int a = 0; a < 2; a++)
#pragma unroll
        for (int g2 = 0; g2 < 2; g2++) acc[a][g2] = (f32x4){0.f, 0.f, 0.f, 0.f};
    float l[2] = {0.f, 0.f};

    const unsigned short* phb = (const unsigned short*)phG + (size_t)b * 4096 * 32;
    const unsigned short* ggb = (const unsigned short*)gG + ((size_t)b << 17);
    unsigned char* Pw = P_s + w * 2560;

    for (int st = 0; st < 16; st++) {
        int m0 = st << 8;
        __syncthreads();
        {   // stage g: 32 c x 256 m bf16
            int c = tid >> 3, seg = tid & 7;
            const uint4* src = (const uint4*)(ggb + (c << 12) + m0 + seg * 32);
            uint4* dst = (uint4*)(g_s + c * 528 + seg * 64);
            dst[0] = src[0]; dst[1] = src[1]; dst[2] = src[2]; dst[3] = src[3];
        }
        __syncthreads();
        for (int cc = 0; cc < 8; cc++) {
            int mloc = cc << 5;
            int mg = m0 + mloc;
            // phi A-frags straight from global (L2-resident, 64B rows)
            s16x8 F0 = *(const s16x8*)(phb + (size_t)(mg + nl) * 32 + 8 * q);
            s16x8 F1 = *(const s16x8*)(phb + (size_t)(mg + 16 + nl) * 32 + 8 * q);
            f32x4 z = (f32x4){0.f, 0.f, 0.f, 0.f};
            f32x4 sc[2][2];
            sc[0][0] = __builtin_amdgcn_mfma_f32_16x16x32_bf16(F0, BT[0], z, 0, 0, 0);
            sc[0][1] = __builtin_amdgcn_mfma_f32_16x16x32_bf16(F0, BT[1], z, 0, 0, 0);
            sc[1][0] = __builtin_amdgcn_mfma_f32_16x16x32_bf16(F1, BT[0], z, 0, 0, 0);
            sc[1][1] = __builtin_amdgcn_mfma_f32_16x16x32_bf16(F1, BT[1], z, 0, 0, 0);
            // p = 2^(s*log2e - shift); write P strip (wave-private, no barrier)
#pragma unroll
            for (int mt = 0; mt < 2; mt++)
#pragma unroll
                for (int ng = 0; ng < 2; ng++) {
                    float p0 = __builtin_amdgcn_exp2f(sc[mt][ng][0]);
                    float p1 = __builtin_amdgcn_exp2f(sc[mt][ng][1]);
                    float p2 = __builtin_amdgcn_exp2f(sc[mt][ng][2]);
                    float p3 = __builtin_amdgcn_exp2f(sc[mt][ng][3]);
                    l[ng] += (p0 + p1) + (p2 + p3);
                    uint2 pv;
                    pv.x = pk_bf16(p0, p1);
                    pv.y = pk_bf16(p2, p3);
                    *(uint2*)(Pw + (16 * ng + nl) * 80 + mt * 32 + q * 8) = pv;
                }
            // PV: A=g, B=P
            s16x8 P0 = *(const s16x8*)(Pw + nl * 80 + q * 16);
            s16x8 P1 = *(const s16x8*)(Pw + (16 + nl) * 80 + q * 16);
            s16x8 G0 = *(const s16x8*)(g_s + nl * 528 + mloc * 2 + q * 16);
            s16x8 G1 = *(const s16x8*)(g_s + (16 + nl) * 528 + mloc * 2 + q * 16);
            acc[0][0] = __builtin_amdgcn_mfma_f32_16x16x32_bf16(G0, P0, acc[0][0], 0, 0, 0);
            acc[0][1] = __builtin_amdgcn_mfma_f32_16x16x32_bf16(G1, P0, acc[0][1], 0, 0, 0);
            acc[1][0] = __builtin_amdgcn_mfma_f32_16x16x32_bf16(G0, P1, acc[1][0], 0, 0, 0);
            acc[1][1] = __builtin_amdgcn_mfma_f32_16x16x32_bf16(G1, P1, acc[1][1], 0, 0, 0);
        }
    }

    // softmax denominators: reduce over q (lane bits 4,5), then normalize
#pragma unroll
    for (int ng = 0; ng < 2; ng++) {
        float v = l[ng];
        v += __shfl_xor(v, 16);
        v += __shfl_xor(v, 32);
        float linv = 1.0f / v;
        acc[ng][0] *= linv;
        acc[ng][1] *= linv;
    }

    __syncthreads();   // g_s reads done; overlay O_s
#pragma unroll
    for (int ng = 0; ng < 2; ng++) {
        int n_loc = w * 32 + ng * 16 + nl;
#pragma unroll
        for (int cg = 0; cg < 2; cg++) {
            uint2 ov;
            ov.x = pk_bf16(acc[ng][cg][0], acc[ng][cg][1]);
            ov.y = pk_bf16(acc[ng][cg][2], acc[ng][cg][3]);
            *(uint2*)(O_s + n_loc * 80 + (cg * 16 + q * 4) * 2) = ov;
        }
    }
    // w_o A-frags: A[row=cc=16*g4+nl][k=c=8q+j]
    s16x8 WO[4];
#pragma unroll
    for (int g4 = 0; g4 < 4; g4++) {
        const float4* wr = (const float4*)(w_o + (size_t)(g4 * 16 + nl) * 32 + q * 8);
        float4 a0 = wr[0], a1 = wr[1];
        WO[g4][0] = (short)f32_bf16(a0.x); WO[g4][1] = (short)f32_bf16(a0.y);
        WO[g4][2] = (short)f32_bf16(a0.z); WO[g4][3] = (short)f32_bf16(a0.w);
        WO[g4][4] = (short)f32_bf16(a1.x); WO[g4][5] = (short)f32_bf16(a1.y);
        WO[g4][6] = (short)f32_bf16(a1.z); WO[g4][7] = (short)f32_bf16(a1.w);
    }
    float gam = gamma[0];
    __syncthreads();

#pragma unroll
    for (int ng = 0; ng < 2; ng++) {
        int nlb = w * 32 + ng * 16;
        s16x8 OB = *(const s16x8*)(O_s + (nlb + nl) * 80 + q * 16);
#pragma unroll
        for (int g4 = 0; g4 < 4; g4++) {
            f32x4 d = (f32x4){0.f, 0.f, 0.f, 0.f};
            d = __builtin_amdgcn_mfma_f32_16x16x32_bf16(WO[g4], OB, d, 0, 0, 0);
#pragma unroll
            for (int r = 0; r < 4; r++) {
                int cc = g4 * 16 + q * 4 + r;
                size_t gi = (((size_t)(b * 64 + cc)) << 14) + n0 + nlb + nl;
                out[gi] = gam * d[r] + x[gi];
            }
        }
    }
}

extern "C" void kernel_launch(void* const* d_in, const int* in_sizes, int n_in,
                              void* d_out, int out_size, void* d_ws, size_t ws_size,
                              hipStream_t stream) {
    const float* x       = (const float*)d_in[0];
    const float* w_theta = (const float*)d_in[1];
    const float* w_phi   = (const float*)d_in[2];
    const float* w_g     = (const float*)d_in[3];
    const float* w_o     = (const float*)d_in[4];
    const float* gamma   = (const float*)d_in[5];
    float* out = (float*)d_out;

    __hip_bfloat16* thG = (__hip_bfloat16*)d_ws;        // 4*8*16384  = 1 MB
    __hip_bfloat16* phG = thG + 524288;                 // 4*4096*32  = 1 MB
    __hip_bfloat16* gG  = phG + 524288;                 // 4*32*4096  = 1 MB

    proj_kernel<<<256, 256, 0, stream>>>(x, w_theta, w_phi, w_g, thG, phG, gG);
    attn_kernel<<<512, 256, 0, stream>>>(thG, phG, gG, w_o, gamma, x, out);
}

// Round 7
// 169.807 us; speedup vs baseline: 5.2326x; 1.0809x over previous
//
#include <hip/hip_runtime.h>
#include <hip/hip_bf16.h>

// SAGAN self-attention, MI355X gfx950. B=4, C=64, H=W=128, N=16384, M=4096.
// fp32 in/out. Round 7: occupancy + VALU cuts.
//  - attn: 512-thr blocks (8 waves x 16 n), grid 512 -> 16 waves/CU (4/SIMD).
//  - pack p->bf16 via v_perm_b32 (3 instr/pair vs 9 manual-RNE).
//  - proj: grid 512 (px-halves), theta relaid [n][8] (uint2 stores, b128 BT load).
// Verified MFMA layouts: A[row=lane&15][k=8q+j], B[k=8q+j][col=lane&15],
// C/D[row=4q+r][col=lane&15].

typedef __attribute__((ext_vector_type(4))) float f32x4;
typedef __attribute__((ext_vector_type(8))) short s16x8;

__device__ __forceinline__ unsigned short f32_bf16(float f) {
    unsigned int u = __float_as_uint(f);
    return (unsigned short)((u + 0x7fffu + ((u >> 16) & 1u)) >> 16);  // RNE
}
__device__ __forceinline__ unsigned int pk_bf16(float a, float b) {
    return (unsigned int)f32_bf16(a) | ((unsigned int)f32_bf16(b) << 16);
}
// fast pack: round-half-up then take high16 of both via one v_perm_b32
__device__ __forceinline__ unsigned int pk_fast(float a, float b) {
    unsigned int au = __float_as_uint(a) + 0x8000u;
    unsigned int bu = __float_as_uint(b) + 0x8000u;
    return __builtin_amdgcn_perm(bu, au, 0x07060302u);  // lo16=a.hi, hi16=b.hi
}

// ---------------- proj: theta/phi/g 1x1 conv + 2x2 maxpool, MFMA ----------------
// Grid 512 = b(4) x mh(64) x ph(2). Block 256 thr = 4 waves.
// Block covers source rows {2mh, 2mh+1}, px in [64ph, 64ph+64) -> 128 pixels.
__global__ __launch_bounds__(256) void proj_kernel(
    const float* __restrict__ x,
    const float* __restrict__ w_theta, const float* __restrict__ w_phi,
    const float* __restrict__ w_g,
    __hip_bfloat16* __restrict__ thG,   // [b][n][8]   (theta * log2e)
    __hip_bfloat16* __restrict__ phG,   // [b][m][32]  (c8=1.0, c9..31=0)
    __hip_bfloat16* __restrict__ gG)    // [b][32][4096]
{
    __shared__ __align__(16) unsigned short x_s[128 * 72];  // [pix][c], 144 B rows
    int tid = threadIdx.x;
    int bx = blockIdx.x;
    int b = bx >> 7, mh = (bx >> 1) & 63, ph = bx & 1;

    // phase 1: load x, cvt bf16, transpose into x_s[pix][c] (each thr: 32 c)
    {
        int pix = tid & 127, chalf = tid >> 7;
        int py = pix >> 6, pxl = pix & 63;
        const float* xp = x + ((size_t)b << 20) + (size_t)(2 * mh + py) * 128
                            + 64 * ph + pxl;
        unsigned short* row = x_s + pix * 72 + chalf * 32;
#pragma unroll
        for (int h2 = 0; h2 < 2; h2++) {
            float v[16];
#pragma unroll
            for (int c = 0; c < 16; c++)
                v[c] = xp[(size_t)(chalf * 32 + h2 * 16 + c) << 14];
            unsigned int pk[8];
#pragma unroll
            for (int h = 0; h < 8; h++) pk[h] = pk_bf16(v[2 * h], v[2 * h + 1]);
            *(uint4*)(row + h2 * 16)     = make_uint4(pk[0], pk[1], pk[2], pk[3]);
            *(uint4*)(row + h2 * 16 + 8) = make_uint4(pk[4], pk[5], pk[6], pk[7]);
        }
    }

    int lane = tid & 63, w = tid >> 6;
    int q = lane >> 4, nl = lane & 15;

    // weight A-frags: A[row=ch_local=nl][k = 32*ks + 8q + j]
    s16x8 A[3][2];
#pragma unroll
    for (int CT = 0; CT < 3; CT++) {
        const float* wsrc;
        float scale = 1.0f;
        if (CT == 0) {
            if (nl < 8) { wsrc = w_theta + nl * 64; scale = 1.44269504f; }
            else        { wsrc = w_phi + (nl - 8) * 64; }
        } else if (CT == 1) wsrc = w_g + nl * 64;
        else                wsrc = w_g + (16 + nl) * 64;
#pragma unroll
        for (int ks = 0; ks < 2; ks++) {
            const float4* p4 = (const float4*)(wsrc + 32 * ks + 8 * q);
            float4 a0 = p4[0], a1 = p4[1];
            s16x8 f;
            f[0] = (short)f32_bf16(a0.x * scale); f[1] = (short)f32_bf16(a0.y * scale);
            f[2] = (short)f32_bf16(a0.z * scale); f[3] = (short)f32_bf16(a0.w * scale);
            f[4] = (short)f32_bf16(a1.x * scale); f[5] = (short)f32_bf16(a1.y * scale);
            f[6] = (short)f32_bf16(a1.z * scale); f[7] = (short)f32_bf16(a1.w * scale);
            A[CT][ks] = f;
        }
    }
    __syncthreads();

    // phase 2: wave w owns px-tiles {w (py=0), w+4 (py=1)}
    f32x4 acc[3][2];
#pragma unroll
    for (int ti = 0; ti < 2; ti++) {
        int tile = w + 4 * ti;
        const unsigned short* rb = x_s + (16 * tile + nl) * 72;
        s16x8 B0 = *(const s16x8*)(rb + 8 * q);
        s16x8 B1 = *(const s16x8*)(rb + 32 + 8 * q);
#pragma unroll
        for (int CT = 0; CT < 3; CT++) {
            f32x4 d = (f32x4){0.f, 0.f, 0.f, 0.f};
            d = __builtin_amdgcn_mfma_f32_16x16x32_bf16(A[CT][0], B0, d, 0, 0, 0);
            d = __builtin_amdgcn_mfma_f32_16x16x32_bf16(A[CT][1], B1, d, 0, 0, 0);
            acc[CT][ti] = d;
        }
    }

    // theta store: [n][8] layout, uint2 per (q<2, ti)
    if (q < 2) {
        unsigned short* thb = (unsigned short*)thG + ((size_t)b << 14) * 8;
#pragma unroll
        for (int ti = 0; ti < 2; ti++) {
            int n = (2 * mh + ti) * 128 + 64 * ph + 16 * w + nl;
            uint2 tv;
            tv.x = pk_bf16(acc[0][ti][0], acc[0][ti][1]);
            tv.y = pk_bf16(acc[0][ti][2], acc[0][ti][3]);
            *(uint2*)(thb + (size_t)n * 8 + 4 * q) = tv;
        }
    }

    // 2x2 maxpool: py via ti-pair, px via shfl_xor(1)
    float pool[3][4];
#pragma unroll
    for (int CT = 0; CT < 3; CT++)
#pragma unroll
        for (int r = 0; r < 4; r++) {
            float a = fmaxf(acc[CT][0][r], acc[CT][1][r]);
            pool[CT][r] = fmaxf(a, __shfl_xor(a, 1));
        }

    int m = mh * 64 + ph * 32 + 8 * w + (nl >> 1);
    unsigned short* pr = (unsigned short*)phG + ((size_t)(b * 4096 + m)) * 32;
    if ((nl & 1) == 0) {
        if (q >= 2) {   // phi channels 4(q-2)+r
            uint2 pv;
            pv.x = pk_bf16(pool[0][0], pool[0][1]);
            pv.y = pk_bf16(pool[0][2], pool[0][3]);
            *(uint2*)(pr + (q - 2) * 4) = pv;
        }
#pragma unroll
        for (int CT = 1; CT < 3; CT++)
#pragma unroll
            for (int r = 0; r < 4; r++) {
                int cg = 16 * (CT - 1) + 4 * q + r;
                ((unsigned short*)gG)[((size_t)(b * 32 + cg) << 12) + m] =
                    f32_bf16(pool[CT][r]);
            }
    } else {
        if (q == 2)      *(uint4*)(pr + 8)  = make_uint4(0x3f80u, 0, 0, 0); // c8=1.0
        else if (q == 3) *(uint4*)(pr + 16) = make_uint4(0, 0, 0, 0);
        else if (q == 1) *(uint4*)(pr + 24) = make_uint4(0, 0, 0, 0);
    }
}

// ---------------- attn: score MFMA -> exp2 -> PV MFMA -> w_o MFMA ----------------
// Grid 512 = b(4) x n-tile(128). Block 512 thr = 8 waves x 16 n.
__global__ __launch_bounds__(512) void attn_kernel(
    const __hip_bfloat16* __restrict__ thG, const __hip_bfloat16* __restrict__ phG,
    const __hip_bfloat16* __restrict__ gG,
    const float* __restrict__ w_o, const float* __restrict__ gamma,
    const float* __restrict__ x, float* __restrict__ out)
{
    __shared__ __align__(16) unsigned char smem[16896 + 10240];
    unsigned char* g_s = smem;                  // [32][528 B]  (256 m bf16 + pad)
    unsigned char* P_s = smem + 16896;          // per-wave [16 n][80 B]
    unsigned char* O_s = smem;                  // epilogue overlay [128][80 B]

    int tid = threadIdx.x, lane = tid & 63, w = tid >> 6;   // w: 0..7
    int q = lane >> 4, nl = lane & 15;
    int bx = blockIdx.x;
    int b  = bx >> 7;
    int n0 = (bx & 127) << 7;
    int nw = n0 + w * 16;

    // theta B-frag: B[k=c=8q+j][col=n=nl]; q0 = theta (one b128), q1 j0 = shift
    const unsigned short* thb = (const unsigned short*)thG + ((size_t)b << 14) * 8;
    s16x8 BT;
    if (q == 0)      BT = *(const s16x8*)(thb + (size_t)(nw + nl) * 8);
    else {
        s16x8 f;
#pragma unroll
        for (int j = 0; j < 8; j++) f[j] = 0;
        if (q == 1) f[0] = (short)0xC167;      // bf16(-14.4375): shift, cancels
        BT = f;
    }

    f32x4 acc[2];
    acc[0] = (f32x4){0.f, 0.f, 0.f, 0.f};
    acc[1] = (f32x4){0.f, 0.f, 0.f, 0.f};
    float l = 0.f;

    const unsigned short* phb = (const unsigned short*)phG + (size_t)b * 4096 * 32;
    const unsigned short* ggb = (const unsigned short*)gG + ((size_t)b << 17);
    unsigned char* Pw = P_s + w * 1280;

    for (int st = 0; st < 16; st++) {
        int m0 = st << 8;
        __syncthreads();
        {   // stage g: 32 c x 256 m bf16 (512 thr x 32 B)
            int c = tid >> 4, s = tid & 15;
            const uint4* src = (const uint4*)(ggb + (c << 12) + m0 + s * 16);
            uint4* dst = (uint4*)(g_s + c * 528 + s * 32);
            dst[0] = src[0]; dst[1] = src[1];
        }
        __syncthreads();
        for (int cc = 0; cc < 8; cc++) {
            int mloc = cc << 5;
            int mg = m0 + mloc;
            // phi A-frags from global (L1/L2-resident)
            s16x8 F0 = *(const s16x8*)(phb + (size_t)(mg + nl) * 32 + 8 * q);
            s16x8 F1 = *(const s16x8*)(phb + (size_t)(mg + 16 + nl) * 32 + 8 * q);
            f32x4 z = (f32x4){0.f, 0.f, 0.f, 0.f};
            f32x4 sc0 = __builtin_amdgcn_mfma_f32_16x16x32_bf16(F0, BT, z, 0, 0, 0);
            f32x4 sc1 = __builtin_amdgcn_mfma_f32_16x16x32_bf16(F1, BT, z, 0, 0, 0);
            // p = 2^(s*log2e - shift)
            float p0 = __builtin_amdgcn_exp2f(sc0[0]);
            float p1 = __builtin_amdgcn_exp2f(sc0[1]);
            float p2 = __builtin_amdgcn_exp2f(sc0[2]);
            float p3 = __builtin_amdgcn_exp2f(sc0[3]);
            float p4 = __builtin_amdgcn_exp2f(sc1[0]);
            float p5 = __builtin_amdgcn_exp2f(sc1[1]);
            float p6 = __builtin_amdgcn_exp2f(sc1[2]);
            float p7 = __builtin_amdgcn_exp2f(sc1[3]);
            l += ((p0 + p1) + (p2 + p3)) + ((p4 + p5) + (p6 + p7));
            // P strip write: row n=nl, m slots 16mt+4q..+3
            *(uint2*)(Pw + nl * 80 + (4 * q) * 2) =
                make_uint2(pk_fast(p0, p1), pk_fast(p2, p3));
            *(uint2*)(Pw + nl * 80 + (16 + 4 * q) * 2) =
                make_uint2(pk_fast(p4, p5), pk_fast(p6, p7));
            // PV: A=g (rows c), B=P (k=m, col=n)
            s16x8 PB = *(const s16x8*)(Pw + nl * 80 + q * 16);
            s16x8 G0 = *(const s16x8*)(g_s + nl * 528 + mloc * 2 + q * 16);
            s16x8 G1 = *(const s16x8*)(g_s + (16 + nl) * 528 + mloc * 2 + q * 16);
            acc[0] = __builtin_amdgcn_mfma_f32_16x16x32_bf16(G0, PB, acc[0], 0, 0, 0);
            acc[1] = __builtin_amdgcn_mfma_f32_16x16x32_bf16(G1, PB, acc[1], 0, 0, 0);
        }
    }

    // softmax denominator: reduce over q (lane bits 4,5)
    l += __shfl_xor(l, 16);
    l += __shfl_xor(l, 32);
    float linv = 1.0f / l;
    acc[0] *= linv;
    acc[1] *= linv;

    // w_o A-frags (global, fp32->bf16): A[row=cc=16g4+nl][k=c=8q+j]
    s16x8 WO[4];
#pragma unroll
    for (int g4 = 0; g4 < 4; g4++) {
        const float4* wr = (const float4*)(w_o + (size_t)(g4 * 16 + nl) * 32 + q * 8);
        float4 a0 = wr[0], a1 = wr[1];
        WO[g4][0] = (short)f32_bf16(a0.x); WO[g4][1] = (short)f32_bf16(a0.y);
        WO[g4][2] = (short)f32_bf16(a0.z); WO[g4][3] = (short)f32_bf16(a0.w);
        WO[g4][4] = (short)f32_bf16(a1.x); WO[g4][5] = (short)f32_bf16(a1.y);
        WO[g4][6] = (short)f32_bf16(a1.z); WO[g4][7] = (short)f32_bf16(a1.w);
    }
    float gam = gamma[0];

    __syncthreads();   // all g_s reads done; overlay O_s
    // O^T[c][n] -> O_s[n_loc][c] bf16 (wave-local rows)
    int n_loc = w * 16 + nl;
#pragma unroll
    for (int cg = 0; cg < 2; cg++) {
        uint2 ov;
        ov.x = pk_bf16(acc[cg][0], acc[cg][1]);
        ov.y = pk_bf16(acc[cg][2], acc[cg][3]);
        *(uint2*)(O_s + n_loc * 80 + (cg * 16 + q * 4) * 2) = ov;
    }
    // wave-local read (DS in-order per wave; rows written by this wave only)
    s16x8 OB = *(const s16x8*)(O_s + (w * 16 + nl) * 80 + q * 16);
#pragma unroll
    for (int g4 = 0; g4 < 4; g4++) {
        f32x4 d = (f32x4){0.f, 0.f, 0.f, 0.f};
        d = __builtin_amdgcn_mfma_f32_16x16x32_bf16(WO[g4], OB, d, 0, 0, 0);
#pragma unroll
        for (int r = 0; r < 4; r++) {
            int cc = g4 * 16 + q * 4 + r;
            size_t gi = (((size_t)(b * 64 + cc)) << 14) + nw + nl;
            out[gi] = gam * d[r] + x[gi];
        }
    }
}

extern "C" void kernel_launch(void* const* d_in, const int* in_sizes, int n_in,
                              void* d_out, int out_size, void* d_ws, size_t ws_size,
                              hipStream_t stream) {
    const float* x       = (const float*)d_in[0];
    const float* w_theta = (const float*)d_in[1];
    const float* w_phi   = (const float*)d_in[2];
    const float* w_g     = (const float*)d_in[3];
    const float* w_o     = (const float*)d_in[4];
    const float* gamma   = (const float*)d_in[5];
    float* out = (float*)d_out;

    __hip_bfloat16* thG = (__hip_bfloat16*)d_ws;        // 4*16384*8 = 1 MB
    __hip_bfloat16* phG = thG + 524288;                 // 4*4096*32 = 1 MB
    __hip_bfloat16* gG  = phG + 524288;                 // 4*32*4096 = 1 MB

    proj_kernel<<<512, 256, 0, stream>>>(x, w_theta, w_phi, w_g, thG, phG, gG);
    attn_kernel<<<512, 512, 0, stream>>>(thG, phG, gG, w_o, gamma, x, out);
}

// Round 8
// 148.682 us; speedup vs baseline: 5.9760x; 1.1421x over previous
//
#include <hip/hip_runtime.h>
#include <hip/hip_bf16.h>

// SAGAN self-attention, MI355X gfx950. B=4, C=64, H=W=128, N=16384, M=4096.
// fp32 in/out. Round 8:
//  - PV via mfma_f32_16x16x16bf16_1k: score-D layout == its B-frag layout ->
//    exp results feed PV in-register, NO P LDS round-trip (bpermute fallback).
//  - phi compact [m][8]; only q==0 lanes load it (8x less L1 traffic).
//  - P pack = 1 v_perm (truncate). proj: float4 loads + u32 LDS transpose.
// Verified MFMA layouts: A[row=lane&15][k=8q+j] (K=32) / [k=4q+j] (K=16),
// B same k-mapping with col=lane&15, C/D[row=4q+r][col=lane&15].

typedef __attribute__((ext_vector_type(4))) float f32x4;
typedef __attribute__((ext_vector_type(8))) short s16x8;
typedef __attribute__((ext_vector_type(4))) short s16x4;

__device__ __forceinline__ unsigned short f32_bf16(float f) {
    unsigned int u = __float_as_uint(f);
    return (unsigned short)((u + 0x7fffu + ((u >> 16) & 1u)) >> 16);  // RNE
}
__device__ __forceinline__ unsigned int pk_bf16(float a, float b) {
    return (unsigned int)f32_bf16(a) | ((unsigned int)f32_bf16(b) << 16);
}
// round-half-up pack: 3 instr
__device__ __forceinline__ unsigned int pk_rh(float a, float b) {
    unsigned int au = __float_as_uint(a) + 0x8000u;
    unsigned int bu = __float_as_uint(b) + 0x8000u;
    return __builtin_amdgcn_perm(bu, au, 0x07060302u);  // lo16=a.hi16, hi16=b.hi16
}
// truncate pack: 1 instr (p>0, rel err <2^-8 -- fine for softmax weights)
__device__ __forceinline__ unsigned int pk_tr(float a, float b) {
    return __builtin_amdgcn_perm(__float_as_uint(b), __float_as_uint(a), 0x07060302u);
}

// ---------------- proj: theta/phi/g 1x1 conv + 2x2 maxpool, MFMA ----------------
// Grid 512 = b(4) x mh(64) x ph(2). Block 256 thr = 4 waves.
__global__ __launch_bounds__(256) void proj_kernel(
    const float* __restrict__ x,
    const float* __restrict__ w_theta, const float* __restrict__ w_phi,
    const float* __restrict__ w_g,
    __hip_bfloat16* __restrict__ thG,   // [b][n][8]  (theta * log2e)
    __hip_bfloat16* __restrict__ phG,   // [b][m][8]
    __hip_bfloat16* __restrict__ gG)    // [b][32][4096]
{
    __shared__ __align__(16) unsigned short x_s[128 * 72];  // [pix][c], 144 B rows
    int tid = threadIdx.x;
    int bx = blockIdx.x;
    int b = bx >> 7, mh = (bx >> 1) & 63, ph = bx & 1;

    // phase 1: float4 loads (c-pair per thread), bf16 c-pair-packed u32 transpose
    {
        int cp = tid >> 3, s = tid & 7;     // cp: 0..31 -> c = {2cp, 2cp+1}
        const float* xb = x + ((size_t)b << 20) + (size_t)(2 * mh) * 128 + 64 * ph;
        const float* p0r = xb + ((size_t)(2 * cp) << 14);
        const float* p1r = p0r + (1 << 14);
#pragma unroll
        for (int py = 0; py < 2; py++)
#pragma unroll
            for (int t = 0; t < 2; t++) {
                int pxl = 4 * s + 32 * t;
                float4 a = *(const float4*)(p0r + py * 128 + pxl);
                float4 c = *(const float4*)(p1r + py * 128 + pxl);
                int pix = py * 64 + pxl;
                *(unsigned int*)&x_s[(pix + 0) * 72 + 2 * cp] = pk_rh(a.x, c.x);
                *(unsigned int*)&x_s[(pix + 1) * 72 + 2 * cp] = pk_rh(a.y, c.y);
                *(unsigned int*)&x_s[(pix + 2) * 72 + 2 * cp] = pk_rh(a.z, c.z);
                *(unsigned int*)&x_s[(pix + 3) * 72 + 2 * cp] = pk_rh(a.w, c.w);
            }
    }

    int lane = tid & 63, w = tid >> 6;
    int q = lane >> 4, nl = lane & 15;

    // weight A-frags: A[row=ch_local=nl][k = 32*ks + 8q + j]
    s16x8 A[3][2];
#pragma unroll
    for (int CT = 0; CT < 3; CT++) {
        const float* wsrc;
        float scale = 1.0f;
        if (CT == 0) {
            if (nl < 8) { wsrc = w_theta + nl * 64; scale = 1.44269504f; }
            else        { wsrc = w_phi + (nl - 8) * 64; }
        } else if (CT == 1) wsrc = w_g + nl * 64;
        else                wsrc = w_g + (16 + nl) * 64;
#pragma unroll
        for (int ks = 0; ks < 2; ks++) {
            const float4* p4 = (const float4*)(wsrc + 32 * ks + 8 * q);
            float4 a0 = p4[0], a1 = p4[1];
            s16x8 f;
            f[0] = (short)f32_bf16(a0.x * scale); f[1] = (short)f32_bf16(a0.y * scale);
            f[2] = (short)f32_bf16(a0.z * scale); f[3] = (short)f32_bf16(a0.w * scale);
            f[4] = (short)f32_bf16(a1.x * scale); f[5] = (short)f32_bf16(a1.y * scale);
            f[6] = (short)f32_bf16(a1.z * scale); f[7] = (short)f32_bf16(a1.w * scale);
            A[CT][ks] = f;
        }
    }
    __syncthreads();

    // phase 2: wave w owns px-tiles {w (py=0), w+4 (py=1)}
    f32x4 acc[3][2];
#pragma unroll
    for (int ti = 0; ti < 2; ti++) {
        int tile = w + 4 * ti;
        const unsigned short* rb = x_s + (16 * tile + nl) * 72;
        s16x8 B0 = *(const s16x8*)(rb + 8 * q);
        s16x8 B1 = *(const s16x8*)(rb + 32 + 8 * q);
#pragma unroll
        for (int CT = 0; CT < 3; CT++) {
            f32x4 d = (f32x4){0.f, 0.f, 0.f, 0.f};
            d = __builtin_amdgcn_mfma_f32_16x16x32_bf16(A[CT][0], B0, d, 0, 0, 0);
            d = __builtin_amdgcn_mfma_f32_16x16x32_bf16(A[CT][1], B1, d, 0, 0, 0);
            acc[CT][ti] = d;
        }
    }

    // theta store: [n][8] layout, uint2 per (q<2, ti)
    if (q < 2) {
        unsigned short* thb = (unsigned short*)thG + ((size_t)b << 14) * 8;
#pragma unroll
        for (int ti = 0; ti < 2; ti++) {
            int n = (2 * mh + ti) * 128 + 64 * ph + 16 * w + nl;
            uint2 tv;
            tv.x = pk_bf16(acc[0][ti][0], acc[0][ti][1]);
            tv.y = pk_bf16(acc[0][ti][2], acc[0][ti][3]);
            *(uint2*)(thb + (size_t)n * 8 + 4 * q) = tv;
        }
    }

    // 2x2 maxpool: py via ti-pair, px via shfl_xor(1)
    float pool[3][4];
#pragma unroll
    for (int CT = 0; CT < 3; CT++)
#pragma unroll
        for (int r = 0; r < 4; r++) {
            float a = fmaxf(acc[CT][0][r], acc[CT][1][r]);
            pool[CT][r] = fmaxf(a, __shfl_xor(a, 1));
        }

    int m = mh * 64 + ph * 32 + 8 * w + (nl >> 1);
    if ((nl & 1) == 0) {
        if (q >= 2) {   // phi channels 4(q-2)+r, compact [m][8]
            uint2 pv;
            pv.x = pk_bf16(pool[0][0], pool[0][1]);
            pv.y = pk_bf16(pool[0][2], pool[0][3]);
            *(uint2*)((unsigned short*)phG + ((size_t)(b * 4096 + m)) * 8 + (q - 2) * 4) = pv;
        }
#pragma unroll
        for (int CT = 1; CT < 3; CT++)
#pragma unroll
            for (int r = 0; r < 4; r++) {
                int cg = 16 * (CT - 1) + 4 * q + r;
                ((unsigned short*)gG)[((size_t)(b * 32 + cg) << 12) + m] =
                    f32_bf16(pool[CT][r]);
            }
    }
}

// ---------------- attn: score MFMA -> exp2 -> PV MFMA (in-register) ----------------
// Grid 512 = b(4) x n-tile(128). Block 512 thr = 8 waves x 16 n.
#define GSTR 528   // g_s row stride bytes (256 m bf16 + 16 pad), 16B-aligned

__global__ __launch_bounds__(512) void attn_kernel(
    const __hip_bfloat16* __restrict__ thG, const __hip_bfloat16* __restrict__ phG,
    const __hip_bfloat16* __restrict__ gG,
    const float* __restrict__ w_o, const float* __restrict__ gamma,
    const float* __restrict__ x, float* __restrict__ out)
{
    __shared__ __align__(16) unsigned char smem[32 * GSTR];
    unsigned char* g_s = smem;      // [32 c][GSTR]
    unsigned char* O_s = smem;      // epilogue overlay [128][80 B]

    int tid = threadIdx.x, lane = tid & 63, w = tid >> 6;   // w: 0..7
    int q = lane >> 4, nl = lane & 15;
    int bx = blockIdx.x;
    int b  = bx >> 7;
    int n0 = (bx & 127) << 7;
    int nw = n0 + w * 16;

    // theta B-frag: B[k=c=8q+j][col=n=nl]; q1 j0 = shift (cancels in softmax)
    const unsigned short* thb = (const unsigned short*)thG + ((size_t)b << 14) * 8;
    s16x8 BT = (s16x8){0, 0, 0, 0, 0, 0, 0, 0};
    if (q == 0)      BT = *(const s16x8*)(thb + (size_t)(nw + nl) * 8);
    else if (q == 1) BT[0] = (short)0xC167;    // bf16(-14.4375)
    // phi A-frag const part: A[row=m][k]: q1 j0 -> k=8 slot = 1.0
    s16x8 Fc = (s16x8){0, 0, 0, 0, 0, 0, 0, 0};
    if (q == 1) Fc[0] = (short)0x3F80;

    f32x4 acc0 = (f32x4){0.f, 0.f, 0.f, 0.f};
    f32x4 acc1 = (f32x4){0.f, 0.f, 0.f, 0.f};
    float l = 0.f;

    const unsigned short* phb = (const unsigned short*)phG + ((size_t)b << 12) * 8;
    const unsigned short* ggb = (const unsigned short*)gG + ((size_t)b << 17);

#if !__has_builtin(__builtin_amdgcn_mfma_f32_16x16x16bf16_1k)
    int ia = ((((2 * q) & 3) * 16 + nl) << 2);       // bpermute byte-idx
    int ib = ((((2 * q + 1) & 3) * 16 + nl) << 2);
#endif

    for (int st = 0; st < 16; st++) {
        int m0 = st << 8;
        __syncthreads();
        {   // stage g: 32 c x 256 m bf16 (512 thr x 32 B)
            int c = tid >> 4, s = tid & 15;
            const uint4* src = (const uint4*)(ggb + (c << 12) + m0 + s * 16);
            uint4* dst = (uint4*)(g_s + c * GSTR + s * 32);
            dst[0] = src[0]; dst[1] = src[1];
        }
        __syncthreads();
#pragma unroll
        for (int cc = 0; cc < 8; cc++) {
            int mloc = cc << 5;
            int mg = m0 + mloc;
            s16x8 F0 = Fc, F1 = Fc;
            if (q == 0) {   // exec-masked: real phi rows, c0..7
                F0 = *(const s16x8*)(phb + (size_t)(mg + nl) * 8);
                F1 = *(const s16x8*)(phb + (size_t)(mg + 16 + nl) * 8);
            }
            f32x4 z = (f32x4){0.f, 0.f, 0.f, 0.f};
            f32x4 sc0 = __builtin_amdgcn_mfma_f32_16x16x32_bf16(F0, BT, z, 0, 0, 0);
            f32x4 sc1 = __builtin_amdgcn_mfma_f32_16x16x32_bf16(F1, BT, z, 0, 0, 0);
            float e0 = __builtin_amdgcn_exp2f(sc0[0]);
            float e1 = __builtin_amdgcn_exp2f(sc0[1]);
            float e2 = __builtin_amdgcn_exp2f(sc0[2]);
            float e3 = __builtin_amdgcn_exp2f(sc0[3]);
            float f0 = __builtin_amdgcn_exp2f(sc1[0]);
            float f1 = __builtin_amdgcn_exp2f(sc1[1]);
            float f2 = __builtin_amdgcn_exp2f(sc1[2]);
            float f3 = __builtin_amdgcn_exp2f(sc1[3]);
            l += ((e0 + e1) + (e2 + e3)) + ((f0 + f1) + (f2 + f3));
            uint2 u0 = make_uint2(pk_tr(e0, e1), pk_tr(e2, e3));   // P rows m=4q+r
            uint2 u1 = make_uint2(pk_tr(f0, f1), pk_tr(f2, f3));   // m=16+4q+r
            const unsigned char* ga = g_s + nl * GSTR + (mloc + 4 * q) * 2;
            const unsigned char* gb = g_s + (nl + 16) * GSTR + (mloc + 4 * q) * 2;
#if __has_builtin(__builtin_amdgcn_mfma_f32_16x16x16bf16_1k)
            // score-D layout == K16 B-frag layout: feed exp directly, no LDS
            s16x4 P0 = *(s16x4*)&u0;
            s16x4 P1 = *(s16x4*)&u1;
            s16x4 G0a = *(const s16x4*)ga;
            s16x4 G0b = *(const s16x4*)(ga + 32);
            s16x4 G1a = *(const s16x4*)gb;
            s16x4 G1b = *(const s16x4*)(gb + 32);
            acc0 = __builtin_amdgcn_mfma_f32_16x16x16bf16_1k(G0a, P0, acc0, 0, 0, 0);
            acc0 = __builtin_amdgcn_mfma_f32_16x16x16bf16_1k(G0b, P1, acc0, 0, 0, 0);
            acc1 = __builtin_amdgcn_mfma_f32_16x16x16bf16_1k(G1a, P0, acc1, 0, 0, 0);
            acc1 = __builtin_amdgcn_mfma_f32_16x16x16bf16_1k(G1b, P1, acc1, 0, 0, 0);
#else
            // fallback: build K=32 B-frag via ds_bpermute (cross-quad gather)
            int r0a = __builtin_amdgcn_ds_bpermute(ia, (int)u0.x);
            int r1a = __builtin_amdgcn_ds_bpermute(ia, (int)u0.y);
            int r2a = __builtin_amdgcn_ds_bpermute(ib, (int)u0.x);
            int r3a = __builtin_amdgcn_ds_bpermute(ib, (int)u0.y);
            int r0b = __builtin_amdgcn_ds_bpermute(ia, (int)u1.x);
            int r1b = __builtin_amdgcn_ds_bpermute(ia, (int)u1.y);
            int r2b = __builtin_amdgcn_ds_bpermute(ib, (int)u1.x);
            int r3b = __builtin_amdgcn_ds_bpermute(ib, (int)u1.y);
            bool hi = q >= 2;
            uint4 Bw = make_uint4(hi ? r0b : r0a, hi ? r1b : r1a,
                                  hi ? r2b : r2a, hi ? r3b : r3a);
            s16x8 PB = *(s16x8*)&Bw;
            s16x8 G0 = *(const s16x8*)(g_s + nl * GSTR + (mloc + 8 * q) * 2);
            s16x8 G1 = *(const s16x8*)(g_s + (nl + 16) * GSTR + (mloc + 8 * q) * 2);
            acc0 = __builtin_amdgcn_mfma_f32_16x16x32_bf16(G0, PB, acc0, 0, 0, 0);
            acc1 = __builtin_amdgcn_mfma_f32_16x16x32_bf16(G1, PB, acc1, 0, 0, 0);
#endif
        }
    }

    // softmax denominator: reduce over q (lane bits 4,5)
    l += __shfl_xor(l, 16);
    l += __shfl_xor(l, 32);
    float linv = 1.0f / l;
    acc0 *= linv;
    acc1 *= linv;

    // w_o A-frags (global, fp32->bf16): A[row=cc=16g4+nl][k=c=8q+j]
    s16x8 WO[4];
#pragma unroll
    for (int g4 = 0; g4 < 4; g4++) {
        const float4* wr = (const float4*)(w_o + (size_t)(g4 * 16 + nl) * 32 + q * 8);
        float4 a0 = wr[0], a1 = wr[1];
        WO[g4][0] = (short)f32_bf16(a0.x); WO[g4][1] = (short)f32_bf16(a0.y);
        WO[g4][2] = (short)f32_bf16(a0.z); WO[g4][3] = (short)f32_bf16(a0.w);
        WO[g4][4] = (short)f32_bf16(a1.x); WO[g4][5] = (short)f32_bf16(a1.y);
        WO[g4][6] = (short)f32_bf16(a1.z); WO[g4][7] = (short)f32_bf16(a1.w);
    }
    float gam = gamma[0];

    __syncthreads();   // all g_s reads done; overlay O_s
    int n_loc = w * 16 + nl;
    {
        uint2 ov;
        ov.x = pk_bf16(acc0[0], acc0[1]);
        ov.y = pk_bf16(acc0[2], acc0[3]);
        *(uint2*)(O_s + n_loc * 80 + (q * 4) * 2) = ov;
        ov.x = pk_bf16(acc1[0], acc1[1]);
        ov.y = pk_bf16(acc1[2], acc1[3]);
        *(uint2*)(O_s + n_loc * 80 + (16 + q * 4) * 2) = ov;
    }
    s16x8 OB = *(const s16x8*)(O_s + n_loc * 80 + q * 16);   // wave-local rows
#pragma unroll
    for (int g4 = 0; g4 < 4; g4++) {
        f32x4 d = (f32x4){0.f, 0.f, 0.f, 0.f};
        d = __builtin_amdgcn_mfma_f32_16x16x32_bf16(WO[g4], OB, d, 0, 0, 0);
#pragma unroll
        for (int r = 0; r < 4; r++) {
            int cc = g4 * 16 + q * 4 + r;
            size_t gi = (((size_t)(b * 64 + cc)) << 14) + nw + nl;
            out[gi] = gam * d[r] + x[gi];
        }
    }
}

extern "C" void kernel_launch(void* const* d_in, const int* in_sizes, int n_in,
                              void* d_out, int out_size, void* d_ws, size_t ws_size,
                              hipStream_t stream) {
    const float* x       = (const float*)d_in[0];
    const float* w_theta = (const float*)d_in[1];
    const float* w_phi   = (const float*)d_in[2];
    const float* w_g     = (const float*)d_in[3];
    const float* w_o     = (const float*)d_in[4];
    const float* gamma   = (const float*)d_in[5];
    float* out = (float*)d_out;

    __hip_bfloat16* thG = (__hip_bfloat16*)d_ws;        // 4*16384*8 = 1 MB
    __hip_bfloat16* phG = thG + 524288;                 // 4*4096*8  = 256 KB
    __hip_bfloat16* gG  = phG + 131072;                 // 4*32*4096 = 1 MB

    proj_kernel<<<512, 256, 0, stream>>>(x, w_theta, w_phi, w_g, thG, phG, gG);
    attn_kernel<<<512, 512, 0, stream>>>(thG, phG, gG, w_o, gamma, x, out);
}